// Round 3
// baseline (5727.433 us; speedup 1.0000x reference)
//
#include <hip/hip_runtime.h>
#include <math.h>

#define NN 50000
#define EE 400000
#define LEE 1600000
#define BBATCH 256
#define FF 64
#define EDD 16
#define NITER 3
#define SFD 384

#define CDIV(a,b) (((a)+(b)-1)/(b))

// ---------- helpers ----------
__device__ inline unsigned f2u_mono(float f) {
    unsigned u = __float_as_uint(f);
    return (u & 0x80000000u) ? ~u : (u | 0x80000000u);
}
__device__ inline float u2f_mono(unsigned u) {
    return (u & 0x80000000u) ? __uint_as_float(u & 0x7fffffffu) : __uint_as_float(~u);
}

// ---------- kernels ----------

// xu = x @ W_u, xv = x @ W_v   ([N,64] @ [64,64])
__global__ void k_node_mm(const float* __restrict__ x, const float* __restrict__ Wu,
                          const float* __restrict__ Wv, float* __restrict__ xu,
                          float* __restrict__ xv) {
    __shared__ float su[64 * 64];
    __shared__ float sv[64 * 64];
    int tid = threadIdx.x;
    for (int i = tid; i < 64 * 64; i += blockDim.x) { su[i] = Wu[i]; sv[i] = Wv[i]; }
    __syncthreads();
    int row = blockIdx.x * (blockDim.x >> 6) + (tid >> 6);
    int f = tid & 63;
    if (row >= NN) return;
    const float* xr = x + (long long)row * 64;
    float au = 0.f, av = 0.f;
    #pragma unroll
    for (int k = 0; k < 64; ++k) {
        float xv_ = xr[k];
        au += xv_ * su[k * 64 + f];
        av += xv_ * sv[k * 64 + f];
    }
    xu[(long long)row * 64 + f] = au;
    xv[(long long)row * 64 + f] = av;
}

// ea[e][f] = (xu[ei0[e]][f] + xv[ei1[e]][f] + edge_attr[e] @ W_e) / 3
__global__ void k_ea(const float* __restrict__ xu, const float* __restrict__ xv,
                     const float* __restrict__ eattr, const float* __restrict__ We,
                     const int* __restrict__ ei, float* __restrict__ ea) {
    __shared__ float swe[16 * 64];
    int tid = threadIdx.x;
    for (int i = tid; i < 16 * 64; i += blockDim.x) swe[i] = We[i];
    __syncthreads();
    int e = blockIdx.x * (blockDim.x >> 6) + (tid >> 6);
    int f = tid & 63;
    if (e >= EE) return;
    int s = ei[e];
    int d = ei[EE + e];
    const float* ar = eattr + (long long)e * 16;
    float acc = 0.f;
    #pragma unroll
    for (int k = 0; k < 16; ++k) acc += ar[k] * swe[k * 64 + f];
    ea[(long long)e * 64 + f] =
        (xu[(long long)s * 64 + f] + xv[(long long)d * 64 + f] + acc) * (1.0f / 3.0f);
}

// out_next += out_prev[lg0] scattered to lg1  (out_next pre-initialized to ea)
__global__ void k_mp_scatter(const float* __restrict__ out_prev, const int* __restrict__ lg,
                             float* __restrict__ out_next) {
    long long idx = (long long)blockIdx.x * blockDim.x + threadIdx.x;
    if (idx >= (long long)LEE * 64) return;
    int le = (int)(idx >> 6);
    int f = (int)(idx & 63);
    int s = lg[le];
    int d = lg[LEE + le];
    atomicAdd(&out_next[(long long)d * 64 + f], out_prev[(long long)s * 64 + f]);
}

// xw[e] = out[e] . gat_W   (one wave per edge)
__global__ void k_xw(const float* __restrict__ out, const float* __restrict__ gatW,
                     float* __restrict__ xw) {
    int tid = threadIdx.x;
    int e = blockIdx.x * (blockDim.x >> 6) + (tid >> 6);
    int f = tid & 63;
    if (e >= EE) return;
    float v = out[(long long)e * 64 + f] * gatW[f];
    #pragma unroll
    for (int o = 32; o > 0; o >>= 1) v += __shfl_down(v, o, 64);
    if (f == 0) xw[e] = v;
}

// alpha pass 1: segment max over dst (encoded atomicMax); mseg pre-zeroed.
// Valid bottom: every dst has a self-loop and any real float encodes > 0.
__global__ void k_gat1(const int* __restrict__ lg, const float* __restrict__ xw,
                       const float* __restrict__ att_s, const float* __restrict__ att_d,
                       unsigned* __restrict__ mseg) {
    int i = blockIdx.x * blockDim.x + threadIdx.x;
    if (i >= LEE + EE) return;
    int s, d;
    if (i < LEE) { s = lg[i]; d = lg[LEE + i]; } else { s = d = i - LEE; }
    float a = xw[s] * att_s[0] + xw[d] * att_d[0];
    if (a < 0.f) a *= 0.2f;
    atomicMax(&mseg[d], f2u_mono(a));
}

// alpha pass 2: e = exp(alpha - m[dst]); s[dst]+=e; xc[dst]+=e*xw[src]
__global__ void k_gat2(const int* __restrict__ lg, const float* __restrict__ xw,
                       const float* __restrict__ att_s, const float* __restrict__ att_d,
                       const unsigned* __restrict__ mseg, float* __restrict__ sseg,
                       float* __restrict__ xc) {
    int i = blockIdx.x * blockDim.x + threadIdx.x;
    if (i >= LEE + EE) return;
    int s, d;
    if (i < LEE) { s = lg[i]; d = lg[LEE + i]; } else { s = d = i - LEE; }
    float a = xw[s] * att_s[0] + xw[d] * att_d[0];
    if (a < 0.f) a *= 0.2f;
    float m = u2f_mono(mseg[d]);
    float ev = expf(a - m);
    atomicAdd(&sseg[d], ev);
    atomicAdd(&xc[d], ev * xw[s]);
}

// xc final: xc = xc/(s+1e-16) + bias
__global__ void k_gat3(float* __restrict__ xc, const float* __restrict__ sseg,
                       const float* __restrict__ gbias) {
    int e = blockIdx.x * blockDim.x + threadIdx.x;
    if (e >= EE) return;
    xc[e] = xc[e] / (sseg[e] + 1e-16f) + gbias[0];
}

// batch rowptr from sorted batch ids
__global__ void k_batchptr(const int* __restrict__ batch, int* __restrict__ bptr) {
    int e = blockIdx.x * blockDim.x + threadIdx.x;
    if (e >= EE) return;
    int b = batch[e];
    int bp = (e == 0) ? -1 : batch[e - 1];
    for (int q = bp + 1; q <= b; ++q) bptr[q] = e;
    if (e == EE - 1)
        for (int q = b + 1; q <= BBATCH; ++q) bptr[q] = EE;
}

// per-batch: softmax(xc) over batch segment, then gout[b] = sum coef*out
__global__ void k_pool(const float* __restrict__ xc, const float* __restrict__ out,
                       const int* __restrict__ bptr, float* __restrict__ gout) {
    int b = blockIdx.x;
    int p0 = bptr[b], p1 = bptr[b + 1];
    __shared__ float red[256];
    int tid = threadIdx.x;
    float mx = -INFINITY;
    for (int e = p0 + tid; e < p1; e += 256) mx = fmaxf(mx, xc[e]);
    red[tid] = mx; __syncthreads();
    for (int s = 128; s > 0; s >>= 1) { if (tid < s) red[tid] = fmaxf(red[tid], red[tid + s]); __syncthreads(); }
    float m = red[0]; __syncthreads();
    float sm = 0.f;
    for (int e = p0 + tid; e < p1; e += 256) sm += expf(xc[e] - m);
    red[tid] = sm; __syncthreads();
    for (int s = 128; s > 0; s >>= 1) { if (tid < s) red[tid] += red[tid + s]; __syncthreads(); }
    float ssum = red[0] + 1e-16f; __syncthreads();
    int f = tid & 63, chunk = tid >> 6;
    float acc = 0.f;
    for (int e = p0 + chunk; e < p1; e += 4) {
        float w = expf(xc[e] - m);
        acc += w * out[(long long)e * 64 + f];
    }
    red[tid] = acc; __syncthreads();
    if (chunk == 0) {
        float tot = red[f] + red[64 + f] + red[128 + f] + red[192 + f];
        gout[b * 64 + f] = tot / ssum;
    }
}

// gt = tanh(gout @ W_gout + b_gout)   ([256,64]@[64,64])
__global__ void k_gout_mm(const float* __restrict__ gout, const float* __restrict__ Wg,
                          const float* __restrict__ bg, float* __restrict__ gt) {
    __shared__ float sw[64 * 64];
    int tid = threadIdx.x;
    for (int i = tid; i < 4096; i += blockDim.x) sw[i] = Wg[i];
    __syncthreads();
    int row = blockIdx.x * (blockDim.x >> 6) + (tid >> 6);
    int f = tid & 63;
    if (row >= BBATCH) return;
    const float* gr = gout + row * 64;
    float acc = bg[f];
    #pragma unroll
    for (int k = 0; k < 64; ++k) acc += gr[k] * sw[k * 64 + f];
    gt[row * 64 + f] = tanhf(acc);
}

// per-batch 3-way attention softmax over iterations (one wave per batch)
__global__ void k_att(const float* __restrict__ g0, const float* __restrict__ g1,
                      const float* __restrict__ g2, const float* __restrict__ a,
                      const float* __restrict__ abias, float* __restrict__ sc) {
    int b = blockIdx.x;
    int f = threadIdx.x; // 64 threads
    float v0 = g0[b * 64 + f] * a[f * 3 + 0];
    float v1 = g1[b * 64 + f] * a[f * 3 + 1];
    float v2 = g2[b * 64 + f] * a[f * 3 + 2];
    #pragma unroll
    for (int o = 32; o > 0; o >>= 1) {
        v0 += __shfl_down(v0, o, 64);
        v1 += __shfl_down(v1, o, 64);
        v2 += __shfl_down(v2, o, 64);
    }
    if (f == 0) {
        float s0 = v0 + abias[0], s1 = v1 + abias[1], s2 = v2 + abias[2];
        float m = fmaxf(s0, fmaxf(s1, s2));
        float e0 = expf(s0 - m), e1 = expf(s1 - m), e2 = expf(s2 - m);
        float inv = 1.0f / (e0 + e1 + e2);
        sc[b * 3 + 0] = e0 * inv; sc[b * 3 + 1] = e1 * inv; sc[b * 3 + 2] = e2 * inv;
    }
}

// xn += scatter over ei1 of out_t * sc_t[batch]   (one iteration's contribution)
__global__ void k_accum(const float* __restrict__ out, const float* __restrict__ sc, int t,
                        const int* __restrict__ batch, const int* __restrict__ ei,
                        float* __restrict__ xn) {
    long long idx = (long long)blockIdx.x * blockDim.x + threadIdx.x;
    if (idx >= (long long)EE * 64) return;
    int e = (int)(idx >> 6);
    int f = (int)(idx & 63);
    float v = out[idx] * sc[batch[e] * 3 + t];
    int d = ei[EE + e];
    atomicAdd(&xn[(long long)d * 64 + f], v);
}

// column sums / sums of squares (blockDim.x == ncols, ncols<=1024)
__global__ void k_colstats(const float* __restrict__ X, int ncols, int nrows,
                           float* __restrict__ csum, float* __restrict__ csumsq) {
    int c = threadIdx.x;
    int rpb = CDIV(nrows, (int)gridDim.x);
    int r0 = blockIdx.x * rpb;
    int r1 = min(r0 + rpb, nrows);
    float s = 0.f, s2 = 0.f;
    for (int r = r0; r < r1; ++r) {
        float v = X[(long long)r * ncols + c];
        s += v; s2 += v * v;
    }
    atomicAdd(&csum[c], s);
    atomicAdd(&csumsq[c], s2);
}

__global__ void k_bnfin(const float* __restrict__ csum, const float* __restrict__ csumsq,
                        int ncols, float* __restrict__ meanv, float* __restrict__ invv) {
    int c = blockIdx.x * blockDim.x + threadIdx.x;
    if (c >= ncols) return;
    float m = csum[c] * (1.0f / NN);
    float var = csumsq[c] * (1.0f / NN) - m * m;
    meanv[c] = m;
    invv[c] = rsqrtf(var + 1e-5f);
}

// C = scale * (act(bn(A)) @ W + bias + res)
// BN+PReLU fused into the A-tile load. act(a) = prelu((a-mean)*inv*g + b).
// pr == nullptr -> no prelu. res may equal C (elementwise-owned). A != C required.
__global__ void k_gemm_bn(const float* __restrict__ A, const float* __restrict__ W,
                          const float* __restrict__ bias, const float* __restrict__ res,
                          const float* __restrict__ meanv, const float* __restrict__ invv,
                          const float* __restrict__ g, const float* __restrict__ bb,
                          const float* __restrict__ pr, float scale,
                          int nrows, int K, int M, float* __restrict__ C) {
    __shared__ float sA[64][17];
    __shared__ float sB[16][64];
    int tid = threadIdx.x;
    int tx = tid & 15;
    int ty = tid >> 4;
    int rowBase = blockIdx.y * 64;
    int colBase = blockIdx.x * 64;
    float prs = pr ? pr[0] : 1.0f;
    float acc[4][4] = {};
    for (int k0 = 0; k0 < K; k0 += 16) {
        // A tile with fused BN-act: column of A = k0+kk
        {
            int kk = tid & 15;
            float scl = invv[k0 + kk] * g[k0 + kk];
            float off = bb[k0 + kk] - meanv[k0 + kk] * scl;
            #pragma unroll
            for (int q = 0; q < 4; ++q) {
                int r = (tid >> 4) + q * 16;
                int gr = rowBase + r;
                float v = (gr < nrows) ? A[(long long)gr * K + k0 + kk] : 0.0f;
                v = v * scl + off;
                if (v < 0.f) v *= prs;
                sA[r][kk] = v;
            }
        }
        #pragma unroll
        for (int q = 0; q < 4; ++q) {
            int kk = (tid >> 6) + q * 4;
            int c = tid & 63;
            sB[kk][c] = W[(long long)(k0 + kk) * M + colBase + c];
        }
        __syncthreads();
        #pragma unroll
        for (int kk = 0; kk < 16; ++kk) {
            float a0 = sA[ty][kk], a1 = sA[ty + 16][kk], a2 = sA[ty + 32][kk], a3 = sA[ty + 48][kk];
            float b0 = sB[kk][tx], b1 = sB[kk][tx + 16], b2 = sB[kk][tx + 32], b3 = sB[kk][tx + 48];
            acc[0][0] += a0 * b0; acc[0][1] += a0 * b1; acc[0][2] += a0 * b2; acc[0][3] += a0 * b3;
            acc[1][0] += a1 * b0; acc[1][1] += a1 * b1; acc[1][2] += a1 * b2; acc[1][3] += a1 * b3;
            acc[2][0] += a2 * b0; acc[2][1] += a2 * b1; acc[2][2] += a2 * b2; acc[2][3] += a2 * b3;
            acc[3][0] += a3 * b0; acc[3][1] += a3 * b1; acc[3][2] += a3 * b2; acc[3][3] += a3 * b3;
        }
        __syncthreads();
    }
    #pragma unroll
    for (int i = 0; i < 4; ++i) {
        int gr = rowBase + ty + 16 * i;
        if (gr >= nrows) continue;
        #pragma unroll
        for (int j = 0; j < 4; ++j) {
            int gc = colBase + tx + 16 * j;
            float v = acc[i][j] + bias[gc];
            if (res) v += res[(long long)gr * M + gc];
            C[(long long)gr * M + gc] = v * scale;
        }
    }
}

extern "C" void kernel_launch(void* const* d_in, const int* in_sizes, int n_in,
                              void* d_out, int out_size, void* d_ws, size_t ws_size,
                              hipStream_t stream) {
    const float* x       = (const float*)d_in[0];
    const float* eattr   = (const float*)d_in[1];
    const int*   ei      = (const int*)d_in[2];
    const int*   lg      = (const int*)d_in[3];
    const int*   batch   = (const int*)d_in[4];
    const float* W_u     = (const float*)d_in[5];
    const float* W_v     = (const float*)d_in[6];
    const float* W_e     = (const float*)d_in[7];
    const float* gat_W   = (const float*)d_in[8];
    const float* att_s   = (const float*)d_in[9];
    const float* att_d   = (const float*)d_in[10];
    const float* gat_b   = (const float*)d_in[11];
    const float* a_att   = (const float*)d_in[12];
    const float* a_bias  = (const float*)d_in[13];
    const float* W_gout  = (const float*)d_in[14];
    const float* b_gout  = (const float*)d_in[15];
    const float* bn1_g   = (const float*)d_in[16];
    const float* bn1_b   = (const float*)d_in[17];
    const float* lb_W1   = (const float*)d_in[18];
    const float* lb_b1   = (const float*)d_in[19];
    const float* lb_bn_g = (const float*)d_in[20];
    const float* lb_bn_b = (const float*)d_in[21];
    const float* lb_pr   = (const float*)d_in[22];
    const float* lb_W    = (const float*)d_in[23];
    const float* lb_b    = (const float*)d_in[24];
    const float* bn5_g   = (const float*)d_in[25];
    const float* bn5_b   = (const float*)d_in[26];
    const float* pr5     = (const float*)d_in[27];
    const float* lb_W5   = (const float*)d_in[28];
    const float* lb_b5   = (const float*)d_in[29];
    float* out_final = (float*)d_out;

    // ---------------- workspace layout (floats), ~250 MB total ----------------
    const long long ESZ = (long long)EE * FF;   // 25.6M
    const long long NSZ = (long long)NN * FF;   // 3.2M
    float* ws = (float*)d_ws;
    float* XU = ws;                             // [N,F]
    float* XV = XU + NSZ;                       // [N,F]
    float* P0 = XV + NSZ;                       // [E,F] ping
    float* P1 = P0 + ESZ;                       // [E,F] pong
    float* XW = P1 + ESZ;                       // [E]
    unsigned* MSEG = (unsigned*)(XW + EE);      // [E]
    float* SSEG = (float*)(MSEG + EE);          // [E]
    float* XC = SSEG + EE;                      // [E]
    float* XN = XC + EE;                        // [N,F]
    float* GRAW = XN + NSZ;                     // [B,F]
    float* G0 = GRAW + BBATCH * FF;             // [B,F] x3
    float* G1 = G0 + BBATCH * FF;
    float* G2 = G1 + BBATCH * FF;
    float* SCATT = G2 + BBATCH * FF;            // [B,3]
    int* BPTR = (int*)(SCATT + BBATCH * 3);     // [B+1]
    float* CSUM = (float*)(BPTR + BBATCH + 4);  // [384] x4
    float* CSUMSQ = CSUM + SFD;
    float* MEANV = CSUMSQ + SFD;
    float* INVV = MEANV + SFD;
    const long long TOTALF = (INVV + SFD) - ws;
    if ((long long)ws_size < TOTALF * 4) return;  // diagnostic: zeros out -> ws too small

    // LinBlock big temps alias the ping-pong buffers ([N,384]=19.2M <= 25.6M each)
    float* T1 = P0;
    float* T2 = P1;
    float* GTS[3] = {G0, G1, G2};

    const int EB = CDIV(EE, 4);       // edge-wave grid
    const int SCB = (int)CDIV((long long)LEE * 64, 256);
    const int ACB = (int)CDIV((long long)EE * 64, 256);
    const int GGB = CDIV(LEE + EE, 256);

    // 1. node transforms + batch rowptr
    k_node_mm<<<CDIV(NN, 4), 256, 0, stream>>>(x, W_u, W_v, XU, XV);
    k_batchptr<<<CDIV(EE, 256), 256, 0, stream>>>(batch, BPTR);

    // GAT + pool + gout macro-sequence on buffer `buf`, result tanh'd into GTS[t]
    auto gat_pool = [&](float* buf, int t) {
        k_xw<<<EB, 256, 0, stream>>>(buf, gat_W, XW);
        hipMemsetAsync(MSEG, 0, (size_t)3 * EE * sizeof(float), stream); // MSEG,SSEG,XC
        k_gat1<<<GGB, 256, 0, stream>>>(lg, XW, att_s, att_d, MSEG);
        k_gat2<<<GGB, 256, 0, stream>>>(lg, XW, att_s, att_d, MSEG, SSEG, XC);
        k_gat3<<<CDIV(EE, 256), 256, 0, stream>>>(XC, SSEG, gat_b);
        k_pool<<<BBATCH, 256, 0, stream>>>(XC, buf, BPTR, GRAW);
        k_gout_mm<<<CDIV(BBATCH, 4), 256, 0, stream>>>(GRAW, W_gout, b_gout, GTS[t]);
    };

    // 2. Pass 1: out_t recurrence with ping-pong; store only pooled gouts.
    // t=0: out1 = ea + S(ea)
    k_ea<<<EB, 256, 0, stream>>>(XU, XV, eattr, W_e, ei, P1);   // P1 = ea (prev)
    k_ea<<<EB, 256, 0, stream>>>(XU, XV, eattr, W_e, ei, P0);   // P0 = ea (cur base)
    k_mp_scatter<<<SCB, 256, 0, stream>>>(P1, lg, P0);          // P0 = out1
    gat_pool(P0, 0);
    // t=1: out2 = ea + S(out1)
    k_ea<<<EB, 256, 0, stream>>>(XU, XV, eattr, W_e, ei, P1);
    k_mp_scatter<<<SCB, 256, 0, stream>>>(P0, lg, P1);          // P1 = out2
    gat_pool(P1, 1);
    // t=2: out3 = ea + S(out2)
    k_ea<<<EB, 256, 0, stream>>>(XU, XV, eattr, W_e, ei, P0);
    k_mp_scatter<<<SCB, 256, 0, stream>>>(P1, lg, P0);          // P0 = out3
    gat_pool(P0, 2);

    // 3. iteration attention weights
    k_att<<<BBATCH, 64, 0, stream>>>(G0, G1, G2, a_att, a_bias, SCATT);

    // 4. Pass 2: xn = x + sum_t scatter(out_t * sc_t).  P0 still holds out3.
    hipMemcpyAsync(XN, x, (size_t)NSZ * sizeof(float), hipMemcpyDeviceToDevice, stream);
    k_accum<<<ACB, 256, 0, stream>>>(P0, SCATT, 2, batch, ei, XN);   // out3 contribution
    // recompute out1
    k_ea<<<EB, 256, 0, stream>>>(XU, XV, eattr, W_e, ei, P1);   // P1 = ea
    k_ea<<<EB, 256, 0, stream>>>(XU, XV, eattr, W_e, ei, P0);   // P0 = ea
    k_mp_scatter<<<SCB, 256, 0, stream>>>(P1, lg, P0);          // P0 = out1
    k_accum<<<ACB, 256, 0, stream>>>(P0, SCATT, 0, batch, ei, XN);
    // recompute out2
    k_ea<<<EB, 256, 0, stream>>>(XU, XV, eattr, W_e, ei, P1);
    k_mp_scatter<<<SCB, 256, 0, stream>>>(P0, lg, P1);          // P1 = out2
    k_accum<<<ACB, 256, 0, stream>>>(P1, SCATT, 1, batch, ei, XN);

    // 5. LinBlock with BN fused into GEMM A-loads. T1=P0, T2=P1 (now dead).
    const long long NSF = (long long)NN * SFD;
    (void)NSF;
    // lin1: T1 = bn1(XN) @ W1 + b1      (no prelu)
    hipMemsetAsync(CSUM, 0, 2 * SFD * sizeof(float), stream);
    k_colstats<<<256, FF, 0, stream>>>(XN, FF, NN, CSUM, CSUMSQ);
    k_bnfin<<<CDIV(FF, 64), 64, 0, stream>>>(CSUM, CSUMSQ, FF, MEANV, INVV);
    {
        dim3 g(SFD / 64, CDIV(NN, 64));
        k_gemm_bn<<<g, 256, 0, stream>>>(XN, lb_W1, lb_b1, nullptr, MEANV, INVV,
                                         bn1_g, bn1_b, nullptr, 1.0f, NN, FF, SFD, T1);
    }
    // lin2: T2 = prelu(bn0(T1)) @ W[0] + b[0]
    hipMemsetAsync(CSUM, 0, 2 * SFD * sizeof(float), stream);
    k_colstats<<<256, SFD, 0, stream>>>(T1, SFD, NN, CSUM, CSUMSQ);
    k_bnfin<<<CDIV(SFD, 64), 64, 0, stream>>>(CSUM, CSUMSQ, SFD, MEANV, INVV);
    {
        dim3 g(SFD / 64, CDIV(NN, 64));
        k_gemm_bn<<<g, 256, 0, stream>>>(T1, lb_W, lb_b, nullptr, MEANV, INVV,
                                         lb_bn_g, lb_bn_b, lb_pr, 1.0f, NN, SFD, SFD, T2);
    }
    // lin3: T1 = (prelu(bn1(T2)) @ W[1] + b[1] + T1) / 2    (res==C==T1, A=T2)
    hipMemsetAsync(CSUM, 0, 2 * SFD * sizeof(float), stream);
    k_colstats<<<256, SFD, 0, stream>>>(T2, SFD, NN, CSUM, CSUMSQ);
    k_bnfin<<<CDIV(SFD, 64), 64, 0, stream>>>(CSUM, CSUMSQ, SFD, MEANV, INVV);
    {
        dim3 g(SFD / 64, CDIV(NN, 64));
        k_gemm_bn<<<g, 256, 0, stream>>>(T2, lb_W + (long long)SFD * SFD, lb_b + SFD, T1,
                                         MEANV, INVV, lb_bn_g + SFD, lb_bn_b + SFD,
                                         lb_pr + 1, 0.5f, NN, SFD, SFD, T1);
    }
    // lin4: T2 = (prelu(bn2(T1)) @ W[2] + b[2] + T1) / 2    (A=res=T1, C=T2)
    hipMemsetAsync(CSUM, 0, 2 * SFD * sizeof(float), stream);
    k_colstats<<<256, SFD, 0, stream>>>(T1, SFD, NN, CSUM, CSUMSQ);
    k_bnfin<<<CDIV(SFD, 64), 64, 0, stream>>>(CSUM, CSUMSQ, SFD, MEANV, INVV);
    {
        dim3 g(SFD / 64, CDIV(NN, 64));
        k_gemm_bn<<<g, 256, 0, stream>>>(T1, lb_W + 2LL * SFD * SFD, lb_b + 2 * SFD, T1,
                                         MEANV, INVV, lb_bn_g + 2 * SFD, lb_bn_b + 2 * SFD,
                                         lb_pr + 2, 0.5f, NN, SFD, SFD, T2);
    }
    // lin5: out = prelu(bn5(T2)) @ W5 + b5
    hipMemsetAsync(CSUM, 0, 2 * SFD * sizeof(float), stream);
    k_colstats<<<256, SFD, 0, stream>>>(T2, SFD, NN, CSUM, CSUMSQ);
    k_bnfin<<<CDIV(SFD, 64), 64, 0, stream>>>(CSUM, CSUMSQ, SFD, MEANV, INVV);
    {
        dim3 g(FF / 64, CDIV(NN, 64));
        k_gemm_bn<<<g, 256, 0, stream>>>(T2, lb_W5, lb_b5, nullptr, MEANV, INVV,
                                         bn5_g, bn5_b, pr5, 1.0f, NN, SFD, FF, out_final);
    }
}

// Round 4
// 4007.182 us; speedup vs baseline: 1.4293x; 1.4293x over previous
//
#include <hip/hip_runtime.h>
#include <math.h>

#define NN 50000
#define EE 400000
#define LEE 1600000
#define BBATCH 256
#define FF 64
#define EDD 16
#define NITER 3
#define SFD 384

#define CDIV(a,b) (((a)+(b)-1)/(b))

typedef unsigned short ushort_t;

// ---------- helpers ----------
__device__ inline unsigned f2u_mono(float f) {
    unsigned u = __float_as_uint(f);
    return (u & 0x80000000u) ? ~u : (u | 0x80000000u);
}
__device__ inline float u2f_mono(unsigned u) {
    return (u & 0x80000000u) ? __uint_as_float(u & 0x7fffffffu) : __uint_as_float(~u);
}
__device__ inline float b2f(ushort_t u) { return __uint_as_float(((unsigned)u) << 16); }
__device__ inline ushort_t f2b(float f) {   // RNE
    unsigned u = __float_as_uint(f);
    return (ushort_t)((u + 0x7fffu + ((u >> 16) & 1u)) >> 16);
}

// ---------- small CSR-build kernels ----------
__global__ void k_hist(const int* __restrict__ idx, int n, int* __restrict__ cnt) {
    int i = blockIdx.x * blockDim.x + threadIdx.x;
    if (i < n) atomicAdd(&cnt[idx[i]], 1);
}
// part[b] = sum of 256-chunk b
__global__ void k_part(const int* __restrict__ in, int n, int* __restrict__ part) {
    __shared__ int s[256];
    int i = blockIdx.x * 256 + threadIdx.x;
    s[threadIdx.x] = (i < n) ? in[i] : 0;
    __syncthreads();
    for (int off = 128; off > 0; off >>= 1) {
        if (threadIdx.x < off) s[threadIdx.x] += s[threadIdx.x + off];
        __syncthreads();
    }
    if (threadIdx.x == 0) part[blockIdx.x] = s[0];
}
// exclusive scan in place, n <= 256, single block
__global__ void k_scan_single(int* __restrict__ a, int n) {
    __shared__ int s[256];
    int v = (threadIdx.x < n) ? a[threadIdx.x] : 0;
    s[threadIdx.x] = v; __syncthreads();
    for (int off = 1; off < 256; off <<= 1) {
        int t = (threadIdx.x >= off) ? s[threadIdx.x - off] : 0;
        __syncthreads(); s[threadIdx.x] += t; __syncthreads();
    }
    if (threadIdx.x < n) a[threadIdx.x] = s[threadIdx.x] - v;
}
// exclusive scan each 256-block of a in place, + off[blockIdx]
__global__ void k_scan_add(int* __restrict__ a, int n, const int* __restrict__ off) {
    __shared__ int s[256];
    int i = blockIdx.x * 256 + threadIdx.x;
    int v = (i < n) ? a[i] : 0;
    s[threadIdx.x] = v; __syncthreads();
    for (int o = 1; o < 256; o <<= 1) {
        int t = (threadIdx.x >= o) ? s[threadIdx.x - o] : 0;
        __syncthreads(); s[threadIdx.x] += t; __syncthreads();
    }
    if (i < n) a[i] = s[threadIdx.x] - v + off[blockIdx.x];
}
// rowptr[i] = exclusive scan of in + boff[block];  rowptr[n] = total
__global__ void k_scan_out(const int* __restrict__ in, int n, const int* __restrict__ boff,
                           int* __restrict__ out) {
    __shared__ int s[256];
    int i = blockIdx.x * 256 + threadIdx.x;
    int v = (i < n) ? in[i] : 0;
    s[threadIdx.x] = v; __syncthreads();
    for (int o = 1; o < 256; o <<= 1) {
        int t = (threadIdx.x >= o) ? s[threadIdx.x - o] : 0;
        __syncthreads(); s[threadIdx.x] += t; __syncthreads();
    }
    if (i < n) out[i] = s[threadIdx.x] - v + boff[blockIdx.x];
    if (i == n - 1) out[n] = s[threadIdx.x] + boff[blockIdx.x];
}
__global__ void k_fill_lg(const int* __restrict__ lg, const int* __restrict__ rowptr,
                          int* __restrict__ cnt, int* __restrict__ srcidx) {
    int i = blockIdx.x * blockDim.x + threadIdx.x;
    if (i >= LEE) return;
    int d = lg[LEE + i];
    int pos = rowptr[d] + atomicAdd(&cnt[d], 1);
    srcidx[pos] = lg[i];
}
__global__ void k_fill_n(const int* __restrict__ ei, const int* __restrict__ rowptr,
                         int* __restrict__ cnt, int* __restrict__ nidx) {
    int i = blockIdx.x * blockDim.x + threadIdx.x;
    if (i >= EE) return;
    int d = ei[EE + i];
    int pos = rowptr[d] + atomicAdd(&cnt[d], 1);
    nidx[pos] = i;
}

// ---------- main kernels ----------

// xu = x @ W_u, xv = x @ W_v
__global__ void k_node_mm(const float* __restrict__ x, const float* __restrict__ Wu,
                          const float* __restrict__ Wv, float* __restrict__ xu,
                          float* __restrict__ xv) {
    __shared__ float su[64 * 64];
    __shared__ float sv[64 * 64];
    int tid = threadIdx.x;
    for (int i = tid; i < 64 * 64; i += blockDim.x) { su[i] = Wu[i]; sv[i] = Wv[i]; }
    __syncthreads();
    int row = blockIdx.x * 4 + (tid >> 6);
    int f = tid & 63;
    if (row >= NN) return;
    const float* xr = x + (long long)row * 64;
    float au = 0.f, av = 0.f;
    #pragma unroll
    for (int k = 0; k < 64; ++k) {
        float xv_ = xr[k];
        au += xv_ * su[k * 64 + f];
        av += xv_ * sv[k * 64 + f];
    }
    xu[(long long)row * 64 + f] = au;
    xv[(long long)row * 64 + f] = av;
}

__device__ inline float ea_val(int e, int f, const float* __restrict__ xu,
                               const float* __restrict__ xv, const float* __restrict__ eattr,
                               const int* __restrict__ ei, const float* __restrict__ swe) {
    int s = ei[e], d = ei[EE + e];
    const float* ar = eattr + (long long)e * 16;
    float acc = 0.f;
    #pragma unroll
    for (int k = 0; k < 16; ++k) acc += ar[k] * swe[k * 64 + f];
    return (xu[(long long)s * 64 + f] + xv[(long long)d * 64 + f] + acc) * (1.0f / 3.0f);
}

// out[d] = ea(d) + sum over in-edges of (use_ea ? ea(src) : prev[src])   (bf16 out)
__global__ void k_mp_gather(const ushort_t* __restrict__ prev, int use_ea,
                            const float* __restrict__ xu, const float* __restrict__ xv,
                            const float* __restrict__ eattr, const float* __restrict__ We,
                            const int* __restrict__ ei,
                            const int* __restrict__ rowptr, const int* __restrict__ srcidx,
                            ushort_t* __restrict__ outb) {
    __shared__ float swe[16 * 64];
    int tid = threadIdx.x;
    for (int i = tid; i < 1024; i += 256) swe[i] = We[i];
    __syncthreads();
    int d = blockIdx.x * 4 + (tid >> 6);
    int f = tid & 63;
    if (d >= EE) return;
    float acc = ea_val(d, f, xu, xv, eattr, ei, swe);
    int p0 = rowptr[d], p1 = rowptr[d + 1];
    if (use_ea) {
        for (int j = p0; j < p1; ++j)
            acc += ea_val(srcidx[j], f, xu, xv, eattr, ei, swe);
    } else {
        for (int j = p0; j < p1; ++j)
            acc += b2f(prev[(long long)srcidx[j] * 64 + f]);
    }
    outb[(long long)d * 64 + f] = f2b(acc);
}

// xw[e] = out[e] . gat_W   (one wave per edge, bf16 input)
__global__ void k_xw(const ushort_t* __restrict__ out, const float* __restrict__ gatW,
                     float* __restrict__ xw) {
    int tid = threadIdx.x;
    int e = blockIdx.x * 4 + (tid >> 6);
    int f = tid & 63;
    if (e >= EE) return;
    float v = b2f(out[(long long)e * 64 + f]) * gatW[f];
    #pragma unroll
    for (int o = 32; o > 0; o >>= 1) v += __shfl_down(v, o, 64);
    if (f == 0) xw[e] = v;
}

__global__ void k_gat1(const int* __restrict__ lg, const float* __restrict__ xw,
                       const float* __restrict__ att_s, const float* __restrict__ att_d,
                       unsigned* __restrict__ mseg) {
    int i = blockIdx.x * blockDim.x + threadIdx.x;
    if (i >= LEE + EE) return;
    int s, d;
    if (i < LEE) { s = lg[i]; d = lg[LEE + i]; } else { s = d = i - LEE; }
    float a = xw[s] * att_s[0] + xw[d] * att_d[0];
    if (a < 0.f) a *= 0.2f;
    atomicMax(&mseg[d], f2u_mono(a));
}

__global__ void k_gat2(const int* __restrict__ lg, const float* __restrict__ xw,
                       const float* __restrict__ att_s, const float* __restrict__ att_d,
                       const unsigned* __restrict__ mseg, float* __restrict__ sseg,
                       float* __restrict__ xc) {
    int i = blockIdx.x * blockDim.x + threadIdx.x;
    if (i >= LEE + EE) return;
    int s, d;
    if (i < LEE) { s = lg[i]; d = lg[LEE + i]; } else { s = d = i - LEE; }
    float a = xw[s] * att_s[0] + xw[d] * att_d[0];
    if (a < 0.f) a *= 0.2f;
    float m = u2f_mono(mseg[d]);
    float ev = expf(a - m);
    atomicAdd(&sseg[d], ev);
    atomicAdd(&xc[d], ev * xw[s]);
}

__global__ void k_gat3(float* __restrict__ xc, const float* __restrict__ sseg,
                       const float* __restrict__ gbias) {
    int e = blockIdx.x * blockDim.x + threadIdx.x;
    if (e >= EE) return;
    xc[e] = xc[e] / (sseg[e] + 1e-16f) + gbias[0];
}

__global__ void k_batchptr(const int* __restrict__ batch, int* __restrict__ bptr) {
    int e = blockIdx.x * blockDim.x + threadIdx.x;
    if (e >= EE) return;
    int b = batch[e];
    int bp = (e == 0) ? -1 : batch[e - 1];
    for (int q = bp + 1; q <= b; ++q) bptr[q] = e;
    if (e == EE - 1)
        for (int q = b + 1; q <= BBATCH; ++q) bptr[q] = EE;
}

// per-batch: softmax(xc) over segment, weighted-sum pool of bf16 out
__global__ void k_pool(const float* __restrict__ xc, const ushort_t* __restrict__ out,
                       const int* __restrict__ bptr, float* __restrict__ gout) {
    int b = blockIdx.x;
    int p0 = bptr[b], p1 = bptr[b + 1];
    __shared__ float red[256];
    int tid = threadIdx.x;
    float mx = -INFINITY;
    for (int e = p0 + tid; e < p1; e += 256) mx = fmaxf(mx, xc[e]);
    red[tid] = mx; __syncthreads();
    for (int s = 128; s > 0; s >>= 1) { if (tid < s) red[tid] = fmaxf(red[tid], red[tid + s]); __syncthreads(); }
    float m = red[0]; __syncthreads();
    float sm = 0.f;
    for (int e = p0 + tid; e < p1; e += 256) sm += expf(xc[e] - m);
    red[tid] = sm; __syncthreads();
    for (int s = 128; s > 0; s >>= 1) { if (tid < s) red[tid] += red[tid + s]; __syncthreads(); }
    float ssum = red[0] + 1e-16f; __syncthreads();
    int f = tid & 63, chunk = tid >> 6;
    float acc = 0.f;
    for (int e = p0 + chunk; e < p1; e += 4) {
        float w = expf(xc[e] - m);
        acc += w * b2f(out[(long long)e * 64 + f]);
    }
    red[tid] = acc; __syncthreads();
    if (chunk == 0) {
        float tot = red[f] + red[64 + f] + red[128 + f] + red[192 + f];
        gout[b * 64 + f] = tot / ssum;
    }
}

__global__ void k_gout_mm(const float* __restrict__ gout, const float* __restrict__ Wg,
                          const float* __restrict__ bg, float* __restrict__ gt) {
    __shared__ float sw[64 * 64];
    int tid = threadIdx.x;
    for (int i = tid; i < 4096; i += blockDim.x) sw[i] = Wg[i];
    __syncthreads();
    int row = blockIdx.x * 4 + (tid >> 6);
    int f = tid & 63;
    if (row >= BBATCH) return;
    const float* gr = gout + row * 64;
    float acc = bg[f];
    #pragma unroll
    for (int k = 0; k < 64; ++k) acc += gr[k] * sw[k * 64 + f];
    gt[row * 64 + f] = tanhf(acc);
}

__global__ void k_att(const float* __restrict__ g0, const float* __restrict__ g1,
                      const float* __restrict__ g2, const float* __restrict__ a,
                      const float* __restrict__ abias, float* __restrict__ sc) {
    int b = blockIdx.x;
    int f = threadIdx.x; // 64 threads
    float v0 = g0[b * 64 + f] * a[f * 3 + 0];
    float v1 = g1[b * 64 + f] * a[f * 3 + 1];
    float v2 = g2[b * 64 + f] * a[f * 3 + 2];
    #pragma unroll
    for (int o = 32; o > 0; o >>= 1) {
        v0 += __shfl_down(v0, o, 64);
        v1 += __shfl_down(v1, o, 64);
        v2 += __shfl_down(v2, o, 64);
    }
    if (f == 0) {
        float s0 = v0 + abias[0], s1 = v1 + abias[1], s2 = v2 + abias[2];
        float m = fmaxf(s0, fmaxf(s1, s2));
        float e0 = expf(s0 - m), e1 = expf(s1 - m), e2 = expf(s2 - m);
        float inv = 1.0f / (e0 + e1 + e2);
        sc[b * 3 + 0] = e0 * inv; sc[b * 3 + 1] = e1 * inv; sc[b * 3 + 2] = e2 * inv;
    }
}

// xn[n] = x[n] + sum over in-edges e of sum_t out_t[e]*sc[batch[e]][t]  (CSR gather)
__global__ void k_node_gather(const ushort_t* __restrict__ o1, const ushort_t* __restrict__ o2,
                              const ushort_t* __restrict__ o3, const float* __restrict__ sc,
                              const int* __restrict__ batch, const int* __restrict__ nrow,
                              const int* __restrict__ nidx, const float* __restrict__ x,
                              float* __restrict__ xn) {
    int tid = threadIdx.x;
    int n = blockIdx.x * 4 + (tid >> 6);
    int f = tid & 63;
    if (n >= NN) return;
    float acc = x[(long long)n * 64 + f];
    int p0 = nrow[n], p1 = nrow[n + 1];
    for (int j = p0; j < p1; ++j) {
        int e = nidx[j];
        int b = batch[e];
        long long off = (long long)e * 64 + f;
        acc += b2f(o1[off]) * sc[b * 3] + b2f(o2[off]) * sc[b * 3 + 1] + b2f(o3[off]) * sc[b * 3 + 2];
    }
    xn[(long long)n * 64 + f] = acc;
}

// column stats
__global__ void k_colstats(const float* __restrict__ X, int ncols, int nrows,
                           float* __restrict__ csum, float* __restrict__ csumsq) {
    int c = threadIdx.x;
    int rpb = CDIV(nrows, (int)gridDim.x);
    int r0 = blockIdx.x * rpb;
    int r1 = min(r0 + rpb, nrows);
    float s = 0.f, s2 = 0.f;
    for (int r = r0; r < r1; ++r) {
        float v = X[(long long)r * ncols + c];
        s += v; s2 += v * v;
    }
    atomicAdd(&csum[c], s);
    atomicAdd(&csumsq[c], s2);
}

__global__ void k_bnfin(const float* __restrict__ csum, const float* __restrict__ csumsq,
                        int ncols, float* __restrict__ meanv, float* __restrict__ invv) {
    int c = blockIdx.x * blockDim.x + threadIdx.x;
    if (c >= ncols) return;
    float m = csum[c] * (1.0f / NN);
    float var = csumsq[c] * (1.0f / NN) - m * m;
    meanv[c] = m;
    invv[c] = rsqrtf(var + 1e-5f);
}

// C = scale * (act(bn(A)) @ W + bias + res), BN+PReLU fused into A-tile load
__global__ void k_gemm_bn(const float* __restrict__ A, const float* __restrict__ W,
                          const float* __restrict__ bias, const float* __restrict__ res,
                          const float* __restrict__ meanv, const float* __restrict__ invv,
                          const float* __restrict__ g, const float* __restrict__ bb,
                          const float* __restrict__ pr, float scale,
                          int nrows, int K, int M, float* __restrict__ C) {
    __shared__ float sA[64][17];
    __shared__ float sB[16][64];
    int tid = threadIdx.x;
    int tx = tid & 15;
    int ty = tid >> 4;
    int rowBase = blockIdx.y * 64;
    int colBase = blockIdx.x * 64;
    float prs = pr ? pr[0] : 1.0f;
    float acc[4][4] = {};
    for (int k0 = 0; k0 < K; k0 += 16) {
        {
            int kk = tid & 15;
            float scl = invv[k0 + kk] * g[k0 + kk];
            float off = bb[k0 + kk] - meanv[k0 + kk] * scl;
            #pragma unroll
            for (int q = 0; q < 4; ++q) {
                int r = (tid >> 4) + q * 16;
                int gr = rowBase + r;
                float v = (gr < nrows) ? A[(long long)gr * K + k0 + kk] : 0.0f;
                v = v * scl + off;
                if (v < 0.f) v *= prs;
                sA[r][kk] = v;
            }
        }
        #pragma unroll
        for (int q = 0; q < 4; ++q) {
            int kk = (tid >> 6) + q * 4;
            int c = tid & 63;
            sB[kk][c] = W[(long long)(k0 + kk) * M + colBase + c];
        }
        __syncthreads();
        #pragma unroll
        for (int kk = 0; kk < 16; ++kk) {
            float a0 = sA[ty][kk], a1 = sA[ty + 16][kk], a2 = sA[ty + 32][kk], a3 = sA[ty + 48][kk];
            float b0 = sB[kk][tx], b1 = sB[kk][tx + 16], b2 = sB[kk][tx + 32], b3 = sB[kk][tx + 48];
            acc[0][0] += a0 * b0; acc[0][1] += a0 * b1; acc[0][2] += a0 * b2; acc[0][3] += a0 * b3;
            acc[1][0] += a1 * b0; acc[1][1] += a1 * b1; acc[1][2] += a1 * b2; acc[1][3] += a1 * b3;
            acc[2][0] += a2 * b0; acc[2][1] += a2 * b1; acc[2][2] += a2 * b2; acc[2][3] += a2 * b3;
            acc[3][0] += a3 * b0; acc[3][1] += a3 * b1; acc[3][2] += a3 * b2; acc[3][3] += a3 * b3;
        }
        __syncthreads();
    }
    #pragma unroll
    for (int i = 0; i < 4; ++i) {
        int gr = rowBase + ty + 16 * i;
        if (gr >= nrows) continue;
        #pragma unroll
        for (int j = 0; j < 4; ++j) {
            int gc = colBase + tx + 16 * j;
            float v = acc[i][j] + bias[gc];
            if (res) v += res[(long long)gr * M + gc];
            C[(long long)gr * M + gc] = v * scale;
        }
    }
}

extern "C" void kernel_launch(void* const* d_in, const int* in_sizes, int n_in,
                              void* d_out, int out_size, void* d_ws, size_t ws_size,
                              hipStream_t stream) {
    const float* x       = (const float*)d_in[0];
    const float* eattr   = (const float*)d_in[1];
    const int*   ei      = (const int*)d_in[2];
    const int*   lg      = (const int*)d_in[3];
    const int*   batch   = (const int*)d_in[4];
    const float* W_u     = (const float*)d_in[5];
    const float* W_v     = (const float*)d_in[6];
    const float* W_e     = (const float*)d_in[7];
    const float* gat_W   = (const float*)d_in[8];
    const float* att_s   = (const float*)d_in[9];
    const float* att_d   = (const float*)d_in[10];
    const float* gat_b   = (const float*)d_in[11];
    const float* a_att   = (const float*)d_in[12];
    const float* a_bias  = (const float*)d_in[13];
    const float* W_gout  = (const float*)d_in[14];
    const float* b_gout  = (const float*)d_in[15];
    const float* bn1_g   = (const float*)d_in[16];
    const float* bn1_b   = (const float*)d_in[17];
    const float* lb_W1   = (const float*)d_in[18];
    const float* lb_b1   = (const float*)d_in[19];
    const float* lb_bn_g = (const float*)d_in[20];
    const float* lb_bn_b = (const float*)d_in[21];
    const float* lb_pr   = (const float*)d_in[22];
    const float* lb_W    = (const float*)d_in[23];
    const float* lb_b    = (const float*)d_in[24];
    const float* bn5_g   = (const float*)d_in[25];
    const float* bn5_b   = (const float*)d_in[26];
    const float* pr5     = (const float*)d_in[27];
    const float* lb_W5   = (const float*)d_in[28];
    const float* lb_b5   = (const float*)d_in[29];
    float* out_final = (float*)d_out;

    // ---------------- workspace layout (~211 MB) ----------------
    const long long ESZ = (long long)EE * FF;
    const long long NSZ = (long long)NN * FF;
    char* cur = (char*)d_ws;
    auto alloc = [&](size_t bytes) -> void* {
        void* p = (void*)cur;
        cur += (bytes + 255) & ~(size_t)255;
        return p;
    };
    float* XU = (float*)alloc(NSZ * 4);
    float* XV = (float*)alloc(NSZ * 4);
    ushort_t* O1 = (ushort_t*)alloc(ESZ * 2);
    ushort_t* O2 = (ushort_t*)alloc(ESZ * 2);
    ushort_t* O3 = (ushort_t*)alloc(ESZ * 2);
    float* XW = (float*)alloc((size_t)EE * 4);
    unsigned* MSEG = (unsigned*)alloc((size_t)EE * 4);
    float* SSEG = (float*)alloc((size_t)EE * 4);
    float* XC = (float*)alloc((size_t)EE * 4);
    float* XN = (float*)alloc(NSZ * 4);
    float* GRAW = (float*)alloc(BBATCH * FF * 4);
    float* G0 = (float*)alloc(BBATCH * FF * 4);
    float* G1 = (float*)alloc(BBATCH * FF * 4);
    float* G2 = (float*)alloc(BBATCH * FF * 4);
    float* SCATT = (float*)alloc(BBATCH * 3 * 4);
    int* BPTR = (int*)alloc((BBATCH + 1) * 4);
    int* LROW = (int*)alloc((size_t)(EE + 1) * 4);
    int* LSRC = (int*)alloc((size_t)LEE * 4);
    int* LCNT = (int*)alloc((size_t)EE * 4);
    int* NROW = (int*)alloc((size_t)(NN + 1) * 4);
    int* NIDX = (int*)alloc((size_t)EE * 4);
    int* NCNT = (int*)alloc((size_t)NN * 4);
    int* SP0 = (int*)alloc(2048 * 4);
    int* SP1 = (int*)alloc(256 * 4);
    float* CSUM = (float*)alloc(SFD * 4);
    float* CSUMSQ = (float*)alloc(SFD * 4);
    float* MEANV = (float*)alloc(SFD * 4);
    float* INVV = (float*)alloc(SFD * 4);
    if ((size_t)(cur - (char*)d_ws) > ws_size) return;  // diagnostic: zeros -> ws too small

    // LinBlock temps alias the O region (dead by then): T1+T2 = 153.6 MB = |O1..O3|
    float* T1 = (float*)O1;
    float* T2 = T1 + (long long)NN * SFD;
    ushort_t* OUTS[3] = {O1, O2, O3};
    float* GTS[3] = {G0, G1, G2};

    // 1. node transforms + batch rowptr
    k_node_mm<<<CDIV(NN, 4), 256, 0, stream>>>(x, W_u, W_v, XU, XV);
    k_batchptr<<<CDIV(EE, 256), 256, 0, stream>>>(batch, BPTR);

    // 2. build line-graph CSR (by dst)
    {
        hipMemsetAsync(LCNT, 0, (size_t)EE * 4, stream);
        k_hist<<<CDIV(LEE, 256), 256, 0, stream>>>(lg + LEE, LEE, LCNT);
        int nb0 = CDIV(EE, 256), nb1 = CDIV(nb0, 256);
        k_part<<<nb0, 256, 0, stream>>>(LCNT, EE, SP0);
        k_part<<<nb1, 256, 0, stream>>>(SP0, nb0, SP1);
        k_scan_single<<<1, 256, 0, stream>>>(SP1, nb1);
        k_scan_add<<<nb1, 256, 0, stream>>>(SP0, nb0, SP1);
        k_scan_out<<<nb0, 256, 0, stream>>>(LCNT, EE, SP0, LROW);
        hipMemsetAsync(LCNT, 0, (size_t)EE * 4, stream);
        k_fill_lg<<<CDIV(LEE, 256), 256, 0, stream>>>(lg, LROW, LCNT, LSRC);
    }
    // 3. build node CSR (by ei1)
    {
        hipMemsetAsync(NCNT, 0, (size_t)NN * 4, stream);
        k_hist<<<CDIV(EE, 256), 256, 0, stream>>>(ei + EE, EE, NCNT);
        int nb0 = CDIV(NN, 256), nb1 = CDIV(nb0, 256);
        k_part<<<nb0, 256, 0, stream>>>(NCNT, NN, SP0);
        k_part<<<nb1, 256, 0, stream>>>(SP0, nb0, SP1);
        k_scan_single<<<1, 256, 0, stream>>>(SP1, nb1);
        k_scan_add<<<nb1, 256, 0, stream>>>(SP0, nb0, SP1);
        k_scan_out<<<nb0, 256, 0, stream>>>(NCNT, NN, SP0, NROW);
        hipMemsetAsync(NCNT, 0, (size_t)NN * 4, stream);
        k_fill_n<<<CDIV(EE, 256), 256, 0, stream>>>(ei, NROW, NCNT, NIDX);
    }

    const int EB = CDIV(EE, 4);
    const int GGB = CDIV(LEE + EE, 256);

    auto gat_pool = [&](ushort_t* buf, int t) {
        k_xw<<<EB, 256, 0, stream>>>(buf, gat_W, XW);
        hipMemsetAsync(MSEG, 0, (size_t)3 * EE * 4, stream);  // MSEG,SSEG,XC contiguous
        k_gat1<<<GGB, 256, 0, stream>>>(lg, XW, att_s, att_d, MSEG);
        k_gat2<<<GGB, 256, 0, stream>>>(lg, XW, att_s, att_d, MSEG, SSEG, XC);
        k_gat3<<<CDIV(EE, 256), 256, 0, stream>>>(XC, SSEG, gat_b);
        k_pool<<<BBATCH, 256, 0, stream>>>(XC, buf, BPTR, GRAW);
        k_gout_mm<<<CDIV(BBATCH, 4), 256, 0, stream>>>(GRAW, W_gout, b_gout, GTS[t]);
    };

    // 4. message-passing iterations (gather form, bf16 out storage)
    k_mp_gather<<<EB, 256, 0, stream>>>(O1, 1, XU, XV, eattr, W_e, ei, LROW, LSRC, O1);
    gat_pool(O1, 0);
    k_mp_gather<<<EB, 256, 0, stream>>>(O1, 0, XU, XV, eattr, W_e, ei, LROW, LSRC, O2);
    gat_pool(O2, 1);
    k_mp_gather<<<EB, 256, 0, stream>>>(O2, 0, XU, XV, eattr, W_e, ei, LROW, LSRC, O3);
    gat_pool(O3, 2);

    // 5. iteration attention + node aggregation (gather, no atomics)
    k_att<<<BBATCH, 64, 0, stream>>>(G0, G1, G2, a_att, a_bias, SCATT);
    k_node_gather<<<CDIV(NN, 4), 256, 0, stream>>>(O1, O2, O3, SCATT, batch, NROW, NIDX, x, XN);

    // 6. LinBlock (BN fused into GEMM A-loads); O region now dead -> T1/T2
    // lin1: T1 = bn1(XN) @ W1 + b1
    hipMemsetAsync(CSUM, 0, 2 * SFD * 4, stream);
    k_colstats<<<256, FF, 0, stream>>>(XN, FF, NN, CSUM, CSUMSQ);
    k_bnfin<<<CDIV(FF, 64), 64, 0, stream>>>(CSUM, CSUMSQ, FF, MEANV, INVV);
    {
        dim3 g(SFD / 64, CDIV(NN, 64));
        k_gemm_bn<<<g, 256, 0, stream>>>(XN, lb_W1, lb_b1, nullptr, MEANV, INVV,
                                         bn1_g, bn1_b, nullptr, 1.0f, NN, FF, SFD, T1);
    }
    // lin2: T2 = prelu(bn0(T1)) @ W[0] + b[0]
    hipMemsetAsync(CSUM, 0, 2 * SFD * 4, stream);
    k_colstats<<<256, SFD, 0, stream>>>(T1, SFD, NN, CSUM, CSUMSQ);
    k_bnfin<<<CDIV(SFD, 64), 64, 0, stream>>>(CSUM, CSUMSQ, SFD, MEANV, INVV);
    {
        dim3 g(SFD / 64, CDIV(NN, 64));
        k_gemm_bn<<<g, 256, 0, stream>>>(T1, lb_W, lb_b, nullptr, MEANV, INVV,
                                         lb_bn_g, lb_bn_b, lb_pr, 1.0f, NN, SFD, SFD, T2);
    }
    // lin3: T1 = (prelu(bn1(T2)) @ W[1] + b[1] + T1) / 2
    hipMemsetAsync(CSUM, 0, 2 * SFD * 4, stream);
    k_colstats<<<256, SFD, 0, stream>>>(T2, SFD, NN, CSUM, CSUMSQ);
    k_bnfin<<<CDIV(SFD, 64), 64, 0, stream>>>(CSUM, CSUMSQ, SFD, MEANV, INVV);
    {
        dim3 g(SFD / 64, CDIV(NN, 64));
        k_gemm_bn<<<g, 256, 0, stream>>>(T2, lb_W + (long long)SFD * SFD, lb_b + SFD, T1,
                                         MEANV, INVV, lb_bn_g + SFD, lb_bn_b + SFD,
                                         lb_pr + 1, 0.5f, NN, SFD, SFD, T1);
    }
    // lin4: T2 = (prelu(bn2(T1)) @ W[2] + b[2] + T1) / 2
    hipMemsetAsync(CSUM, 0, 2 * SFD * 4, stream);
    k_colstats<<<256, SFD, 0, stream>>>(T1, SFD, NN, CSUM, CSUMSQ);
    k_bnfin<<<CDIV(SFD, 64), 64, 0, stream>>>(CSUM, CSUMSQ, SFD, MEANV, INVV);
    {
        dim3 g(SFD / 64, CDIV(NN, 64));
        k_gemm_bn<<<g, 256, 0, stream>>>(T1, lb_W + 2LL * SFD * SFD, lb_b + 2 * SFD, T1,
                                         MEANV, INVV, lb_bn_g + 2 * SFD, lb_bn_b + 2 * SFD,
                                         lb_pr + 2, 0.5f, NN, SFD, SFD, T2);
    }
    // lin5: out = prelu(bn5(T2)) @ W5 + b5
    hipMemsetAsync(CSUM, 0, 2 * SFD * 4, stream);
    k_colstats<<<256, SFD, 0, stream>>>(T2, SFD, NN, CSUM, CSUMSQ);
    k_bnfin<<<CDIV(SFD, 64), 64, 0, stream>>>(CSUM, CSUMSQ, SFD, MEANV, INVV);
    {
        dim3 g(FF / 64, CDIV(NN, 64));
        k_gemm_bn<<<g, 256, 0, stream>>>(T2, lb_W5, lb_b5, nullptr, MEANV, INVV,
                                         bn5_g, bn5_b, pr5, 1.0f, NN, SFD, FF, out_final);
    }
}

// Round 5
// 2135.876 us; speedup vs baseline: 2.6815x; 1.8761x over previous
//
#include <hip/hip_runtime.h>
#include <math.h>

#define NN 50000
#define EE 400000
#define LEE 1600000
#define BBATCH 256
#define FF 64
#define EDD 16
#define NITER 3
#define SFD 384

#define CDIV(a,b) (((a)+(b)-1)/(b))

typedef unsigned short ushort_t;
typedef __attribute__((ext_vector_type(8))) short bf16x8;
typedef __attribute__((ext_vector_type(4))) float f32x4;

// ---------- helpers ----------
__device__ inline float b2f(ushort_t u) { return __uint_as_float(((unsigned)u) << 16); }
__device__ inline ushort_t f2b(float f) {   // RNE
    unsigned u = __float_as_uint(f);
    return (ushort_t)((u + 0x7fffu + ((u >> 16) & 1u)) >> 16);
}

// ---------- small CSR-build kernels ----------
__global__ void k_hist(const int* __restrict__ idx, int n, int* __restrict__ cnt) {
    int i = blockIdx.x * blockDim.x + threadIdx.x;
    if (i < n) atomicAdd(&cnt[idx[i]], 1);
}
__global__ void k_part(const int* __restrict__ in, int n, int* __restrict__ part) {
    __shared__ int s[256];
    int i = blockIdx.x * 256 + threadIdx.x;
    s[threadIdx.x] = (i < n) ? in[i] : 0;
    __syncthreads();
    for (int off = 128; off > 0; off >>= 1) {
        if (threadIdx.x < off) s[threadIdx.x] += s[threadIdx.x + off];
        __syncthreads();
    }
    if (threadIdx.x == 0) part[blockIdx.x] = s[0];
}
__global__ void k_scan_single(int* __restrict__ a, int n) {
    __shared__ int s[256];
    int v = (threadIdx.x < n) ? a[threadIdx.x] : 0;
    s[threadIdx.x] = v; __syncthreads();
    for (int off = 1; off < 256; off <<= 1) {
        int t = (threadIdx.x >= off) ? s[threadIdx.x - off] : 0;
        __syncthreads(); s[threadIdx.x] += t; __syncthreads();
    }
    if (threadIdx.x < n) a[threadIdx.x] = s[threadIdx.x] - v;
}
__global__ void k_scan_add(int* __restrict__ a, int n, const int* __restrict__ off) {
    __shared__ int s[256];
    int i = blockIdx.x * 256 + threadIdx.x;
    int v = (i < n) ? a[i] : 0;
    s[threadIdx.x] = v; __syncthreads();
    for (int o = 1; o < 256; o <<= 1) {
        int t = (threadIdx.x >= o) ? s[threadIdx.x - o] : 0;
        __syncthreads(); s[threadIdx.x] += t; __syncthreads();
    }
    if (i < n) a[i] = s[threadIdx.x] - v + off[blockIdx.x];
}
__global__ void k_scan_out(const int* __restrict__ in, int n, const int* __restrict__ boff,
                           int* __restrict__ out) {
    __shared__ int s[256];
    int i = blockIdx.x * 256 + threadIdx.x;
    int v = (i < n) ? in[i] : 0;
    s[threadIdx.x] = v; __syncthreads();
    for (int o = 1; o < 256; o <<= 1) {
        int t = (threadIdx.x >= o) ? s[threadIdx.x - o] : 0;
        __syncthreads(); s[threadIdx.x] += t; __syncthreads();
    }
    if (i < n) out[i] = s[threadIdx.x] - v + boff[blockIdx.x];
    if (i == n - 1) out[n] = s[threadIdx.x] + boff[blockIdx.x];
}
__global__ void k_fill_lg(const int* __restrict__ lg, const int* __restrict__ rowptr,
                          int* __restrict__ cnt, int* __restrict__ srcidx) {
    int i = blockIdx.x * blockDim.x + threadIdx.x;
    if (i >= LEE) return;
    int d = lg[LEE + i];
    int pos = rowptr[d] + atomicAdd(&cnt[d], 1);
    srcidx[pos] = lg[i];
}
__global__ void k_fill_n(const int* __restrict__ ei, const int* __restrict__ rowptr,
                         int* __restrict__ cnt, int* __restrict__ nidx) {
    int i = blockIdx.x * blockDim.x + threadIdx.x;
    if (i >= EE) return;
    int d = ei[EE + i];
    int pos = rowptr[d] + atomicAdd(&cnt[d], 1);
    nidx[pos] = i;
}

// ---------- main kernels ----------

// xu = x @ W_u, xv = x @ W_v
__global__ void k_node_mm(const float* __restrict__ x, const float* __restrict__ Wu,
                          const float* __restrict__ Wv, float* __restrict__ xu,
                          float* __restrict__ xv) {
    __shared__ float su[64 * 64];
    __shared__ float sv[64 * 64];
    int tid = threadIdx.x;
    for (int i = tid; i < 64 * 64; i += blockDim.x) { su[i] = Wu[i]; sv[i] = Wv[i]; }
    __syncthreads();
    int row = blockIdx.x * 4 + (tid >> 6);
    int f = tid & 63;
    if (row >= NN) return;
    const float* xr = x + (long long)row * 64;
    float au = 0.f, av = 0.f;
    #pragma unroll
    for (int k = 0; k < 64; ++k) {
        float xv_ = xr[k];
        au += xv_ * su[k * 64 + f];
        av += xv_ * sv[k * 64 + f];
    }
    xu[(long long)row * 64 + f] = au;
    xv[(long long)row * 64 + f] = av;
}

// eab[e][f] = bf16( (xu[ei0] + xv[ei1] + eattr @ W_e) / 3 )
__global__ void k_ea_b16(const float* __restrict__ xu, const float* __restrict__ xv,
                         const float* __restrict__ eattr, const float* __restrict__ We,
                         const int* __restrict__ ei, ushort_t* __restrict__ eab) {
    __shared__ float swe[16 * 64];
    int tid = threadIdx.x;
    for (int i = tid; i < 1024; i += 256) swe[i] = We[i];
    __syncthreads();
    int e = blockIdx.x * 4 + (tid >> 6);
    int f = tid & 63;
    if (e >= EE) return;
    int s = ei[e];
    int d = ei[EE + e];
    const float* ar = eattr + (long long)e * 16;
    float acc = 0.f;
    #pragma unroll
    for (int k = 0; k < 16; ++k) acc += ar[k] * swe[k * 64 + f];
    float v = (xu[(long long)s * 64 + f] + xv[(long long)d * 64 + f] + acc) * (1.0f / 3.0f);
    eab[(long long)e * 64 + f] = f2b(v);
}

// out[d] = eab[d] + sum_{src in-edges} prev[src]; also xw[d] = out[d].gatW
__global__ void k_mp_gather(const ushort_t* __restrict__ prev,
                            const ushort_t* __restrict__ eab,
                            const int* __restrict__ rowptr, const int* __restrict__ srcidx,
                            const float* __restrict__ gatW,
                            ushort_t* __restrict__ outb, float* __restrict__ xw) {
    int tid = threadIdx.x;
    int d = blockIdx.x * 4 + (tid >> 6);
    int f = tid & 63;
    if (d >= EE) return;
    float acc = b2f(eab[(long long)d * 64 + f]);
    int p0 = rowptr[d], p1 = rowptr[d + 1];
    int j = p0;
    for (; j + 4 <= p1; j += 4) {
        int s0 = srcidx[j], s1 = srcidx[j + 1], s2 = srcidx[j + 2], s3 = srcidx[j + 3];
        float v0 = b2f(prev[(long long)s0 * 64 + f]);
        float v1 = b2f(prev[(long long)s1 * 64 + f]);
        float v2 = b2f(prev[(long long)s2 * 64 + f]);
        float v3 = b2f(prev[(long long)s3 * 64 + f]);
        acc += (v0 + v1) + (v2 + v3);
    }
    for (; j < p1; ++j)
        acc += b2f(prev[(long long)srcidx[j] * 64 + f]);
    outb[(long long)d * 64 + f] = f2b(acc);
    float w = acc * gatW[f];
    #pragma unroll
    for (int o = 32; o > 0; o >>= 1) w += __shfl_down(w, o, 64);
    if (f == 0) xw[d] = w;
}

// fused GAT: per dst edge, serial max / exp-sum / weighted-sum over CSR in-edges + self-loop
__global__ void k_gat_fused(const float* __restrict__ xw,
                            const int* __restrict__ rowptr, const int* __restrict__ srcidx,
                            const float* __restrict__ att_s, const float* __restrict__ att_d,
                            const float* __restrict__ gbias, float* __restrict__ xc) {
    int e = blockIdx.x * blockDim.x + threadIdx.x;
    if (e >= EE) return;
    float as = att_s[0], ad = att_d[0];
    float xwd = xw[e];
    float adt = xwd * ad;
    float aself = xwd * as + adt;
    if (aself < 0.f) aself *= 0.2f;
    int p0 = rowptr[e], p1 = rowptr[e + 1];
    float m = aself;
    for (int j = p0; j < p1; ++j) {
        float a = xw[srcidx[j]] * as + adt;
        if (a < 0.f) a *= 0.2f;
        m = fmaxf(m, a);
    }
    float ssum = expf(aself - m);
    float wsum = ssum * xwd;
    for (int j = p0; j < p1; ++j) {
        float xs = xw[srcidx[j]];
        float a = xs * as + adt;
        if (a < 0.f) a *= 0.2f;
        float ev = expf(a - m);
        ssum += ev;
        wsum += ev * xs;
    }
    xc[e] = wsum / (ssum + 1e-16f) + gbias[0];
}

__global__ void k_batchptr(const int* __restrict__ batch, int* __restrict__ bptr) {
    int e = blockIdx.x * blockDim.x + threadIdx.x;
    if (e >= EE) return;
    int b = batch[e];
    int bp = (e == 0) ? -1 : batch[e - 1];
    for (int q = bp + 1; q <= b; ++q) bptr[q] = e;
    if (e == EE - 1)
        for (int q = b + 1; q <= BBATCH; ++q) bptr[q] = EE;
}

// per-batch: softmax(xc) over segment, weighted-sum pool of bf16 out
__global__ void k_pool(const float* __restrict__ xc, const ushort_t* __restrict__ out,
                       const int* __restrict__ bptr, float* __restrict__ gout) {
    int b = blockIdx.x;
    int p0 = bptr[b], p1 = bptr[b + 1];
    __shared__ float red[256];
    int tid = threadIdx.x;
    float mx = -INFINITY;
    for (int e = p0 + tid; e < p1; e += 256) mx = fmaxf(mx, xc[e]);
    red[tid] = mx; __syncthreads();
    for (int s = 128; s > 0; s >>= 1) { if (tid < s) red[tid] = fmaxf(red[tid], red[tid + s]); __syncthreads(); }
    float m = red[0]; __syncthreads();
    float sm = 0.f;
    for (int e = p0 + tid; e < p1; e += 256) sm += expf(xc[e] - m);
    red[tid] = sm; __syncthreads();
    for (int s = 128; s > 0; s >>= 1) { if (tid < s) red[tid] += red[tid + s]; __syncthreads(); }
    float ssum = red[0] + 1e-16f; __syncthreads();
    int f = tid & 63, chunk = tid >> 6;
    float acc = 0.f;
    for (int e = p0 + chunk; e < p1; e += 4) {
        float w = expf(xc[e] - m);
        acc += w * b2f(out[(long long)e * 64 + f]);
    }
    red[tid] = acc; __syncthreads();
    if (chunk == 0) {
        float tot = red[f] + red[64 + f] + red[128 + f] + red[192 + f];
        gout[b * 64 + f] = tot / ssum;
    }
}

__global__ void k_gout_mm(const float* __restrict__ gout, const float* __restrict__ Wg,
                          const float* __restrict__ bg, float* __restrict__ gt) {
    __shared__ float sw[64 * 64];
    int tid = threadIdx.x;
    for (int i = tid; i < 4096; i += blockDim.x) sw[i] = Wg[i];
    __syncthreads();
    int row = blockIdx.x * 4 + (tid >> 6);
    int f = tid & 63;
    if (row >= BBATCH) return;
    const float* gr = gout + row * 64;
    float acc = bg[f];
    #pragma unroll
    for (int k = 0; k < 64; ++k) acc += gr[k] * sw[k * 64 + f];
    gt[row * 64 + f] = tanhf(acc);
}

__global__ void k_att(const float* __restrict__ g0, const float* __restrict__ g1,
                      const float* __restrict__ g2, const float* __restrict__ a,
                      const float* __restrict__ abias, float* __restrict__ sc) {
    int b = blockIdx.x;
    int f = threadIdx.x; // 64 threads
    float v0 = g0[b * 64 + f] * a[f * 3 + 0];
    float v1 = g1[b * 64 + f] * a[f * 3 + 1];
    float v2 = g2[b * 64 + f] * a[f * 3 + 2];
    #pragma unroll
    for (int o = 32; o > 0; o >>= 1) {
        v0 += __shfl_down(v0, o, 64);
        v1 += __shfl_down(v1, o, 64);
        v2 += __shfl_down(v2, o, 64);
    }
    if (f == 0) {
        float s0 = v0 + abias[0], s1 = v1 + abias[1], s2 = v2 + abias[2];
        float m = fmaxf(s0, fmaxf(s1, s2));
        float e0 = expf(s0 - m), e1 = expf(s1 - m), e2 = expf(s2 - m);
        float inv = 1.0f / (e0 + e1 + e2);
        sc[b * 3 + 0] = e0 * inv; sc[b * 3 + 1] = e1 * inv; sc[b * 3 + 2] = e2 * inv;
    }
}

// o1 <- sum_t o_t * sc_t[batch]   (elementwise, in place on o1)
__global__ void k_comb(ushort_t* __restrict__ o1, const ushort_t* __restrict__ o2,
                       const ushort_t* __restrict__ o3, const float* __restrict__ sc,
                       const int* __restrict__ batch) {
    long long idx = (long long)blockIdx.x * blockDim.x + threadIdx.x;
    if (idx >= (long long)EE * 64) return;
    int e = (int)(idx >> 6);
    int b = batch[e];
    float v = b2f(o1[idx]) * sc[b * 3] + b2f(o2[idx]) * sc[b * 3 + 1] + b2f(o3[idx]) * sc[b * 3 + 2];
    o1[idx] = f2b(v);
}

// xn[n] = x[n] + sum over in-edges of comb[e]   (CSR gather)
__global__ void k_node_gather(const ushort_t* __restrict__ comb, const int* __restrict__ nrow,
                              const int* __restrict__ nidx, const float* __restrict__ x,
                              float* __restrict__ xn) {
    int tid = threadIdx.x;
    int n = blockIdx.x * 4 + (tid >> 6);
    int f = tid & 63;
    if (n >= NN) return;
    float acc = x[(long long)n * 64 + f];
    int p0 = nrow[n], p1 = nrow[n + 1];
    int j = p0;
    for (; j + 4 <= p1; j += 4) {
        int e0 = nidx[j], e1 = nidx[j + 1], e2 = nidx[j + 2], e3 = nidx[j + 3];
        float v0 = b2f(comb[(long long)e0 * 64 + f]);
        float v1 = b2f(comb[(long long)e1 * 64 + f]);
        float v2 = b2f(comb[(long long)e2 * 64 + f]);
        float v3 = b2f(comb[(long long)e3 * 64 + f]);
        acc += (v0 + v1) + (v2 + v3);
    }
    for (; j < p1; ++j) acc += b2f(comb[(long long)nidx[j] * 64 + f]);
    xn[(long long)n * 64 + f] = acc;
}

// column stats
__global__ void k_colstats(const float* __restrict__ X, int ncols, int nrows,
                           float* __restrict__ csum, float* __restrict__ csumsq) {
    int c = threadIdx.x;
    int rpb = CDIV(nrows, (int)gridDim.x);
    int r0 = blockIdx.x * rpb;
    int r1 = min(r0 + rpb, nrows);
    float s = 0.f, s2 = 0.f;
    for (int r = r0; r < r1; ++r) {
        float v = X[(long long)r * ncols + c];
        s += v; s2 += v * v;
    }
    atomicAdd(&csum[c], s);
    atomicAdd(&csumsq[c], s2);
}

__global__ void k_bnfin(const float* __restrict__ csum, const float* __restrict__ csumsq,
                        int ncols, float* __restrict__ meanv, float* __restrict__ invv) {
    int c = blockIdx.x * blockDim.x + threadIdx.x;
    if (c >= ncols) return;
    float m = csum[c] * (1.0f / NN);
    float var = csumsq[c] * (1.0f / NN) - m * m;
    meanv[c] = m;
    invv[c] = rsqrtf(var + 1e-5f);
}

// C = scale * (act(bn(A)) @ W + bias + res), MFMA bf16, f32 accumulate.
// Tile 64x64, 4 waves each computing a 32x32 quadrant via 2x2 16x16x32 frags.
__global__ __launch_bounds__(256) void k_gemm_bn_mfma(
    const float* __restrict__ A, const float* __restrict__ W,
    const float* __restrict__ bias, const float* __restrict__ res,
    const float* __restrict__ meanv, const float* __restrict__ invv,
    const float* __restrict__ g, const float* __restrict__ bb,
    const float* __restrict__ pr, float scale,
    int nrows, int K, int M, float* __restrict__ C) {
    __shared__ ushort_t sA[64][40];   // [row][k], pad->80B stride (16B aligned)
    __shared__ ushort_t sB[64][40];   // [col][k], transposed W tile
    __shared__ float sScl[SFD], sOff[SFD];
    int tid = threadIdx.x;
    int wave = tid >> 6, lane = tid & 63;
    int l16 = lane & 15, klo = lane >> 4;
    long long rowBase = (long long)blockIdx.y * 64;
    int colBase = blockIdx.x * 64;
    int wr = (wave >> 1) * 32, wc = (wave & 1) * 32;
    float prs = pr ? pr[0] : 1.0f;
    // precompute BN affine per K-column
    for (int c = tid; c < K; c += 256) {
        float scl = invv[c] * g[c];
        sScl[c] = scl;
        sOff[c] = bb[c] - meanv[c] * scl;
    }
    __syncthreads();
    f32x4 acc[2][2] = {};
    for (int k0 = 0; k0 < K; k0 += 32) {
        // stage A: 64 rows x 32 k (f32 -> bn/act -> bf16)
        #pragma unroll
        for (int rep = 0; rep < 2; ++rep) {
            int i4 = (rep * 256 + tid) * 4;
            int r = i4 >> 5, kk = i4 & 31;
            long long gr = rowBase + r;
            float fv[4] = {0.f, 0.f, 0.f, 0.f};
            if (gr < nrows) {
                const float4 v = *(const float4*)&A[gr * K + k0 + kk];
                fv[0] = v.x; fv[1] = v.y; fv[2] = v.z; fv[3] = v.w;
            }
            union { ushort_t u[4]; uint2 v2; } pk;
            #pragma unroll
            for (int j = 0; j < 4; ++j) {
                int c = k0 + kk + j;
                float t = fv[j] * sScl[c] + sOff[c];
                if (t < 0.f) t *= prs;
                pk.u[j] = f2b(t);
            }
            *(uint2*)&sA[r][kk] = pk.v2;
        }
        // stage B: 32 k-rows x 64 cols of W, transposed into sB[col][k]
        {
            int col = lane;
            int kbase = wave * 8;
            union { ushort_t u[8]; uint4 v4; } pk;
            #pragma unroll
            for (int i = 0; i < 8; ++i)
                pk.u[i] = f2b(W[(long long)(k0 + kbase + i) * M + colBase + col]);
            *(uint4*)&sB[col][kbase] = pk.v4;
        }
        __syncthreads();
        bf16x8 af[2], bf[2];
        #pragma unroll
        for (int m = 0; m < 2; ++m)
            af[m] = *(const bf16x8*)&sA[wr + m * 16 + l16][klo * 8];
        #pragma unroll
        for (int n = 0; n < 2; ++n)
            bf[n] = *(const bf16x8*)&sB[wc + n * 16 + l16][klo * 8];
        #pragma unroll
        for (int m = 0; m < 2; ++m)
            #pragma unroll
            for (int n = 0; n < 2; ++n)
                acc[m][n] = __builtin_amdgcn_mfma_f32_16x16x32_bf16(af[m], bf[n], acc[m][n], 0, 0, 0);
        __syncthreads();
    }
    // epilogue: C/D layout col=lane&15, row=(lane>>4)*4+reg (m89-verified)
    #pragma unroll
    for (int m = 0; m < 2; ++m) {
        #pragma unroll
        for (int n = 0; n < 2; ++n) {
            int col = colBase + wc + n * 16 + l16;
            long long row0 = rowBase + wr + m * 16 + klo * 4;
            #pragma unroll
            for (int r = 0; r < 4; ++r) {
                long long row = row0 + r;
                if (row < nrows) {
                    float v = acc[m][n][r] + bias[col];
                    if (res) v += res[row * M + col];
                    C[row * M + col] = v * scale;
                }
            }
        }
    }
}

extern "C" void kernel_launch(void* const* d_in, const int* in_sizes, int n_in,
                              void* d_out, int out_size, void* d_ws, size_t ws_size,
                              hipStream_t stream) {
    const float* x       = (const float*)d_in[0];
    const float* eattr   = (const float*)d_in[1];
    const int*   ei      = (const int*)d_in[2];
    const int*   lg      = (const int*)d_in[3];
    const int*   batch   = (const int*)d_in[4];
    const float* W_u     = (const float*)d_in[5];
    const float* W_v     = (const float*)d_in[6];
    const float* W_e     = (const float*)d_in[7];
    const float* gat_W   = (const float*)d_in[8];
    const float* att_s   = (const float*)d_in[9];
    const float* att_d   = (const float*)d_in[10];
    const float* gat_b   = (const float*)d_in[11];
    const float* a_att   = (const float*)d_in[12];
    const float* a_bias  = (const float*)d_in[13];
    const float* W_gout  = (const float*)d_in[14];
    const float* b_gout  = (const float*)d_in[15];
    const float* bn1_g   = (const float*)d_in[16];
    const float* bn1_b   = (const float*)d_in[17];
    const float* lb_W1   = (const float*)d_in[18];
    const float* lb_b1   = (const float*)d_in[19];
    const float* lb_bn_g = (const float*)d_in[20];
    const float* lb_bn_b = (const float*)d_in[21];
    const float* lb_pr   = (const float*)d_in[22];
    const float* lb_W    = (const float*)d_in[23];
    const float* lb_b    = (const float*)d_in[24];
    const float* bn5_g   = (const float*)d_in[25];
    const float* bn5_b   = (const float*)d_in[26];
    const float* pr5     = (const float*)d_in[27];
    const float* lb_W5   = (const float*)d_in[28];
    const float* lb_b5   = (const float*)d_in[29];
    float* out_final = (float*)d_out;

    // ---------------- workspace layout (~211 MB) ----------------
    const long long ESZ = (long long)EE * FF;
    const long long NSZ = (long long)NN * FF;
    char* cur = (char*)d_ws;
    auto alloc = [&](size_t bytes) -> void* {
        void* p = (void*)cur;
        cur += (bytes + 255) & ~(size_t)255;
        return p;
    };
    float* XU = (float*)alloc(NSZ * 4);
    float* XV = (float*)alloc(NSZ * 4);
    ushort_t* O1 = (ushort_t*)alloc(ESZ * 2);
    ushort_t* O2 = (ushort_t*)alloc(ESZ * 2);
    ushort_t* O3 = (ushort_t*)alloc(ESZ * 2);   // holds EAB until iter-3 overwrites it
    float* XW = (float*)alloc((size_t)EE * 4);
    float* XC = (float*)alloc((size_t)EE * 4);
    float* XN = (float*)alloc(NSZ * 4);
    float* GRAW = (float*)alloc(BBATCH * FF * 4);
    float* G0 = (float*)alloc(BBATCH * FF * 4);
    float* G1 = (float*)alloc(BBATCH * FF * 4);
    float* G2 = (float*)alloc(BBATCH * FF * 4);
    float* SCATT = (float*)alloc(BBATCH * 3 * 4);
    int* BPTR = (int*)alloc((BBATCH + 1) * 4);
    int* LROW = (int*)alloc((size_t)(EE + 1) * 4);
    int* LSRC = (int*)alloc((size_t)LEE * 4);
    int* LCNT = (int*)alloc((size_t)EE * 4);
    int* NROW = (int*)alloc((size_t)(NN + 1) * 4);
    int* NIDX = (int*)alloc((size_t)EE * 4);
    int* NCNT = (int*)alloc((size_t)NN * 4);
    int* SP0 = (int*)alloc(2048 * 4);
    int* SP1 = (int*)alloc(256 * 4);
    float* CSUM = (float*)alloc(SFD * 4);
    float* CSUMSQ = (float*)alloc(SFD * 4);
    float* MEANV = (float*)alloc(SFD * 4);
    float* INVV = (float*)alloc(SFD * 4);
    if ((size_t)(cur - (char*)d_ws) > ws_size) return;  // diagnostic: zeros -> ws too small

    // LinBlock temps alias the O region (dead by then): 2 x 76.8 MB <= 153.6 MB
    float* T1 = (float*)O1;
    float* T2 = T1 + (long long)NN * SFD;
    float* GTS[3] = {G0, G1, G2};

    // 1. node transforms + batch rowptr
    k_node_mm<<<CDIV(NN, 4), 256, 0, stream>>>(x, W_u, W_v, XU, XV);
    k_batchptr<<<CDIV(EE, 256), 256, 0, stream>>>(batch, BPTR);

    // 2. build line-graph CSR (by dst)
    {
        hipMemsetAsync(LCNT, 0, (size_t)EE * 4, stream);
        k_hist<<<CDIV(LEE, 256), 256, 0, stream>>>(lg + LEE, LEE, LCNT);
        int nb0 = CDIV(EE, 256), nb1 = CDIV(nb0, 256);
        k_part<<<nb0, 256, 0, stream>>>(LCNT, EE, SP0);
        k_part<<<nb1, 256, 0, stream>>>(SP0, nb0, SP1);
        k_scan_single<<<1, 256, 0, stream>>>(SP1, nb1);
        k_scan_add<<<nb1, 256, 0, stream>>>(SP0, nb0, SP1);
        k_scan_out<<<nb0, 256, 0, stream>>>(LCNT, EE, SP0, LROW);
        hipMemsetAsync(LCNT, 0, (size_t)EE * 4, stream);
        k_fill_lg<<<CDIV(LEE, 256), 256, 0, stream>>>(lg, LROW, LCNT, LSRC);
    }
    // 3. build node CSR (by ei1)
    {
        hipMemsetAsync(NCNT, 0, (size_t)NN * 4, stream);
        k_hist<<<CDIV(EE, 256), 256, 0, stream>>>(ei + EE, EE, NCNT);
        int nb0 = CDIV(NN, 256), nb1 = CDIV(nb0, 256);
        k_part<<<nb0, 256, 0, stream>>>(NCNT, NN, SP0);
        k_part<<<nb1, 256, 0, stream>>>(SP0, nb0, SP1);
        k_scan_single<<<1, 256, 0, stream>>>(SP1, nb1);
        k_scan_add<<<nb1, 256, 0, stream>>>(SP0, nb0, SP1);
        k_scan_out<<<nb0, 256, 0, stream>>>(NCNT, NN, SP0, NROW);
        hipMemsetAsync(NCNT, 0, (size_t)NN * 4, stream);
        k_fill_n<<<CDIV(EE, 256), 256, 0, stream>>>(ei, NROW, NCNT, NIDX);
    }

    const int EB = CDIV(EE, 4);

    auto gat_pool = [&](ushort_t* buf, int t) {
        k_gat_fused<<<CDIV(EE, 256), 256, 0, stream>>>(XW, LROW, LSRC, att_s, att_d, gat_b, XC);
        k_pool<<<BBATCH, 256, 0, stream>>>(XC, buf, BPTR, GRAW);
        k_gout_mm<<<CDIV(BBATCH, 4), 256, 0, stream>>>(GRAW, W_gout, b_gout, GTS[t]);
    };

    // 4. EAB + message-passing iterations (uniform gathers, bf16 storage)
    k_ea_b16<<<EB, 256, 0, stream>>>(XU, XV, eattr, W_e, ei, O3);             // O3 = EAB
    k_mp_gather<<<EB, 256, 0, stream>>>(O3, O3, LROW, LSRC, gat_W, O1, XW);   // O1 = out1
    gat_pool(O1, 0);
    k_mp_gather<<<EB, 256, 0, stream>>>(O1, O3, LROW, LSRC, gat_W, O2, XW);   // O2 = out2
    gat_pool(O2, 1);
    k_mp_gather<<<EB, 256, 0, stream>>>(O2, O3, LROW, LSRC, gat_W, O3, XW);   // O3 = out3 (self-term element-owned)
    gat_pool(O3, 2);

    // 5. iteration attention + combine + node aggregation
    k_att<<<BBATCH, 64, 0, stream>>>(G0, G1, G2, a_att, a_bias, SCATT);
    k_comb<<<(int)CDIV(ESZ, 256), 256, 0, stream>>>(O1, O2, O3, SCATT, batch);
    k_node_gather<<<CDIV(NN, 4), 256, 0, stream>>>(O1, NROW, NIDX, x, XN);

    // 6. LinBlock: BN fused into MFMA GEMM A-loads; O region now dead -> T1/T2
    // lin1: T1 = bn1(XN) @ W1 + b1
    hipMemsetAsync(CSUM, 0, 2 * SFD * 4, stream);
    k_colstats<<<256, FF, 0, stream>>>(XN, FF, NN, CSUM, CSUMSQ);
    k_bnfin<<<CDIV(FF, 64), 64, 0, stream>>>(CSUM, CSUMSQ, FF, MEANV, INVV);
    {
        dim3 g(SFD / 64, CDIV(NN, 64));
        k_gemm_bn_mfma<<<g, 256, 0, stream>>>(XN, lb_W1, lb_b1, nullptr, MEANV, INVV,
                                              bn1_g, bn1_b, nullptr, 1.0f, NN, FF, SFD, T1);
    }
    // lin2: T2 = prelu(bn0(T1)) @ W[0] + b[0]
    hipMemsetAsync(CSUM, 0, 2 * SFD * 4, stream);
    k_colstats<<<256, SFD, 0, stream>>>(T1, SFD, NN, CSUM, CSUMSQ);
    k_bnfin<<<CDIV(SFD, 64), 64, 0, stream>>>(CSUM, CSUMSQ, SFD, MEANV, INVV);
    {
        dim3 g(SFD / 64, CDIV(NN, 64));
        k_gemm_bn_mfma<<<g, 256, 0, stream>>>(T1, lb_W, lb_b, nullptr, MEANV, INVV,
                                              lb_bn_g, lb_bn_b, lb_pr, 1.0f, NN, SFD, SFD, T2);
    }
    // lin3: T1 = (prelu(bn1(T2)) @ W[1] + b[1] + T1) / 2
    hipMemsetAsync(CSUM, 0, 2 * SFD * 4, stream);
    k_colstats<<<256, SFD, 0, stream>>>(T2, SFD, NN, CSUM, CSUMSQ);
    k_bnfin<<<CDIV(SFD, 64), 64, 0, stream>>>(CSUM, CSUMSQ, SFD, MEANV, INVV);
    {
        dim3 g(SFD / 64, CDIV(NN, 64));
        k_gemm_bn_mfma<<<g, 256, 0, stream>>>(T2, lb_W + (long long)SFD * SFD, lb_b + SFD, T1,
                                              MEANV, INVV, lb_bn_g + SFD, lb_bn_b + SFD,
                                              lb_pr + 1, 0.5f, NN, SFD, SFD, T1);
    }
    // lin4: T2 = (prelu(bn2(T1)) @ W[2] + b[2] + T1) / 2
    hipMemsetAsync(CSUM, 0, 2 * SFD * 4, stream);
    k_colstats<<<256, SFD, 0, stream>>>(T1, SFD, NN, CSUM, CSUMSQ);
    k_bnfin<<<CDIV(SFD, 64), 64, 0, stream>>>(CSUM, CSUMSQ, SFD, MEANV, INVV);
    {
        dim3 g(SFD / 64, CDIV(NN, 64));
        k_gemm_bn_mfma<<<g, 256, 0, stream>>>(T1, lb_W + 2LL * SFD * SFD, lb_b + 2 * SFD, T1,
                                              MEANV, INVV, lb_bn_g + 2 * SFD, lb_bn_b + 2 * SFD,
                                              lb_pr + 2, 0.5f, NN, SFD, SFD, T2);
    }
    // lin5: out = prelu(bn5(T2)) @ W5 + b5
    hipMemsetAsync(CSUM, 0, 2 * SFD * 4, stream);
    k_colstats<<<256, SFD, 0, stream>>>(T2, SFD, NN, CSUM, CSUMSQ);
    k_bnfin<<<CDIV(SFD, 64), 64, 0, stream>>>(CSUM, CSUMSQ, SFD, MEANV, INVV);
    {
        dim3 g(FF / 64, CDIV(NN, 64));
        k_gemm_bn_mfma<<<g, 256, 0, stream>>>(T2, lb_W5, lb_b5, nullptr, MEANV, INVV,
                                              bn5_g, bn5_b, pr5, 1.0f, NN, SFD, FF, out_final);
    }
}